// Round 13
// baseline (300.832 us; speedup 1.0000x reference)
//
#include <hip/hip_runtime.h>
#include <hip/hip_fp16.h>
#include <math.h>

#define N_NODES  100000
#define N_EDGES  3200000
#define N_GRAPHS 512
#define N_FEAT   128
#define DIM      10
#define PH       16      // fp16 row stride (halves) = 32B, row 32B-aligned
#define OUT      16
#define NBLK     ((N_NODES + 255) / 256)

#define BW       256                         // nodes per bucket
#define BSHIFT   8
#define NBUCK    ((N_NODES + BW - 1) / BW)   // 391
#define NBLK_E   128                         // blocks in edge passes (small frontier set)
#define EPB      ((N_EDGES + NBLK_E - 1) / NBLK_E)  // 25000
#define CAP      12288                       // LDS edge staging per bucket (48KB)
#define NODEBLK  ((N_NODES + 63) / 64)       // 1563 blocks of 64 nodes
#define LAYBLK   ((N_NODES * 16 + 255) / 256) // 6250 blocks, 16 nodes each
#define PWIN     8                           // LDS pool window (graphs per block)

// gptr[g] = first node with batch >= g (batch sorted). gptr[N_GRAPHS] = N_NODES.
__global__ void k_bounds(const int* __restrict__ batch, int* __restrict__ gptr) {
    int n = blockIdx.x * blockDim.x + threadIdx.x;
    if (n >= N_NODES) return;
    int bn = batch[n];
    int bp = (n == 0) ? -1 : batch[n - 1];
    for (int g = bp + 1; g <= bn; ++g) gptr[g] = n;
    if (n == N_NODES - 1)
        for (int g = bn + 1; g <= N_GRAPHS; ++g) gptr[g] = N_NODES;
}

// p[n] = x[n] @ w1 (128->10). 4 lanes/node, interleaved k, DPP-only reduce.
__global__ void k_proj1(const float* __restrict__ x, const float* __restrict__ w1,
                        ushort* __restrict__ pt) {
    __shared__ __align__(16) float s_w1[N_FEAT * 12];
    int tid = threadIdx.x;
    for (int i = tid; i < N_FEAT * DIM; i += 256) {
        int k = i / DIM, f = i - k * DIM;
        s_w1[k * 12 + f] = w1[i];
    }
    __syncthreads();
    int n  = blockIdx.x * 64 + (tid >> 2);
    int sl = tid & 3;
    if (n >= N_NODES) return;

    float4 xv[8];
#pragma unroll
    for (int i = 0; i < 8; ++i)
        xv[i] = *(const float4*)&x[n * N_FEAT + i * 16 + sl * 4];

    float acc[DIM] = {0.f,0.f,0.f,0.f,0.f,0.f,0.f,0.f,0.f,0.f};
#pragma unroll
    for (int i = 0; i < 8; ++i) {
#pragma unroll
        for (int c = 0; c < 4; ++c) {
            float xk = (c == 0) ? xv[i].x : (c == 1) ? xv[i].y : (c == 2) ? xv[i].z : xv[i].w;
            const float* wr = &s_w1[(i * 16 + sl * 4 + c) * 12];
            float4 wa = *(const float4*)wr;
            float4 wb = *(const float4*)(wr + 4);
            float2 wc = *(const float2*)(wr + 8);
            acc[0] += xk * wa.x; acc[1] += xk * wa.y; acc[2] += xk * wa.z; acc[3] += xk * wa.w;
            acc[4] += xk * wb.x; acc[5] += xk * wb.y; acc[6] += xk * wb.z; acc[7] += xk * wb.w;
            acc[8] += xk * wc.x; acc[9] += xk * wc.y;
        }
    }
#pragma unroll
    for (int f = 0; f < DIM; ++f) {
        acc[f] += __shfl_xor(acc[f], 1);
        acc[f] += __shfl_xor(acc[f], 2);
    }
    if (sl == 0) {
        union { __half2 h; unsigned u; } c0, c1, c2, c3, c4;
        c0.h = __floats2half2_rn(acc[0], acc[1]);
        c1.h = __floats2half2_rn(acc[2], acc[3]);
        c2.h = __floats2half2_rn(acc[4], acc[5]);
        c3.h = __floats2half2_rn(acc[6], acc[7]);
        c4.h = __floats2half2_rn(acc[8], acc[9]);
        uint4 s; s.x = c0.u; s.y = c1.u; s.z = c2.u; s.w = c3.u;
        *(uint4*)&pt[n * PH] = s;
        *(unsigned*)&pt[n * PH + 8] = c4.u;
    }
}

// ---- deterministic bucket sort of edges by dst>>BSHIFT (no global atomics) ----
__global__ void k_hist(const int* __restrict__ ei, int* __restrict__ hist) {
    __shared__ int s_h[NBUCK];
    for (int i = threadIdx.x; i < NBUCK; i += blockDim.x) s_h[i] = 0;
    __syncthreads();
    int base = blockIdx.x * EPB;
    int end  = min(base + EPB, N_EDGES);
    for (int e = base + threadIdx.x; e < end; e += blockDim.x)
        atomicAdd(&s_h[ei[N_EDGES + e] >> BSHIFT], 1);
    __syncthreads();
    for (int i = threadIdx.x; i < NBUCK; i += blockDim.x)
        hist[i * NBLK_E + blockIdx.x] = s_h[i];
}

__global__ void k_btot(const int* __restrict__ hist, int* __restrict__ bbase) {
    int b = blockIdx.x, lane = threadIdx.x;
    int t = 0;
    for (int k = lane; k < NBLK_E; k += 64) t += hist[b * NBLK_E + k];
    t += __shfl_xor(t, 32); t += __shfl_xor(t, 16); t += __shfl_xor(t, 8);
    t += __shfl_xor(t, 4);  t += __shfl_xor(t, 2);  t += __shfl_xor(t, 1);
    if (lane == 0) bbase[b] = t;
}

__global__ void k_bscan(int* __restrict__ bbase, int* __restrict__ rowp) {
    __shared__ int s[1024];
    int tid = threadIdx.x;
    int v = (tid < NBUCK) ? bbase[tid] : 0;
    s[tid] = v;
    __syncthreads();
    for (int off = 1; off < 1024; off <<= 1) {
        int w = (tid >= off) ? s[tid - off] : 0;
        __syncthreads();
        s[tid] += w;
        __syncthreads();
    }
    if (tid < NBUCK) bbase[tid] = s[tid] - v;
    if (tid == 0) { bbase[NBUCK] = s[1023]; rowp[N_NODES] = s[1023]; }
}

__global__ void k_colscan(int* __restrict__ hist, const int* __restrict__ bbase) {
    __shared__ int s[NBLK_E];
    int b = blockIdx.x, tid = threadIdx.x;
    int v = hist[b * NBLK_E + tid];
    s[tid] = v;
    __syncthreads();
    for (int off = 1; off < NBLK_E; off <<= 1) {
        int w = (tid >= off) ? s[tid - off] : 0;
        __syncthreads();
        s[tid] += w;
        __syncthreads();
    }
    hist[b * NBLK_E + tid] = bbase[b] + s[tid] - v;
}

__global__ void k_bucket(const int* __restrict__ ei, const int* __restrict__ off,
                         int* __restrict__ col) {
    __shared__ int loc[NBUCK];
    for (int i = threadIdx.x; i < NBUCK; i += blockDim.x)
        loc[i] = off[i * NBLK_E + blockIdx.x];
    __syncthreads();
    int base = blockIdx.x * EPB;
    int end  = min(base + EPB, N_EDGES);
    for (int e = base + threadIdx.x; e < end; e += blockDim.x) {
        int src = ei[e];
        int dst = ei[N_EDGES + e];
        int bkt = dst >> BSHIFT;
        int pos = atomicAdd(&loc[bkt], 1);         // LDS atomic
        col[pos] = ((dst & (BW - 1)) << 17) | src;
    }
}

__global__ void k_sort(const int* __restrict__ bbase, int* __restrict__ col,
                       int* __restrict__ rowp) {
    __shared__ int s_e[CAP];
    __shared__ int s_cnt[BW];
    __shared__ int s_scan[BW];
    __shared__ int s_cur[BW];
    int b = blockIdx.x, tid = threadIdx.x;
    int beg = bbase[b], end = bbase[b + 1], m = end - beg;
    for (int i = tid; i < m; i += 256) s_e[i] = col[beg + i];
    if (tid < BW) s_cnt[tid] = 0;
    __syncthreads();
    for (int i = tid; i < m; i += 256) atomicAdd(&s_cnt[s_e[i] >> 17], 1);
    __syncthreads();
    if (tid < BW) s_scan[tid] = s_cnt[tid];
    __syncthreads();
    for (int off = 1; off < BW; off <<= 1) {
        int v = (tid < BW && tid >= off) ? s_scan[tid - off] : 0;
        __syncthreads();
        if (tid < BW) s_scan[tid] += v;
        __syncthreads();
    }
    if (tid < BW) {
        int excl = s_scan[tid] - s_cnt[tid];
        s_cur[tid] = excl;
        int n = b * BW + tid;
        if (n < N_NODES) rowp[n] = beg + excl;
    }
    __syncthreads();
    for (int i = tid; i < m; i += 256) {
        int pk = s_e[i];
        int pos = atomicAdd(&s_cur[pk >> 17], 1);
        col[beg + pos] = pk & 0x1FFFF;
    }
}

// ---- fused layer: 16 lanes/node batched gather + lane0 MLP + LDS-window pool + proj ----
template <int HAS_NEXT>
__global__ void k_layer(const ushort* __restrict__ pt, const int* __restrict__ rowp,
                        const int* __restrict__ col, const int* __restrict__ batch,
                        const float* __restrict__ b1, const float* __restrict__ w2,
                        const float* __restrict__ b2, const float* __restrict__ w1n,
                        float* __restrict__ poolL, ushort* __restrict__ pn) {
    __shared__ __align__(16) float s_w2[120], s_w1n[120];
    __shared__ float s_b1[DIM], s_b2[DIM];
    __shared__ float s_pool[PWIN * DIM];
    __shared__ int s_gmin;
    int tid = threadIdx.x;
    if (tid < 120) {
        int j = tid / 12, f = tid - j * 12;
        s_w2[tid] = (f < 10) ? w2[j * 10 + f] : 0.f;
        if (HAS_NEXT) s_w1n[tid] = (f < 10) ? w1n[j * 10 + f] : 0.f;
    }
    if (tid < DIM) { s_b1[tid] = b1[tid]; s_b2[tid] = b2[tid]; }
    if (tid < PWIN * DIM) s_pool[tid] = 0.f;
    if (tid == 0) {
        int idx = (int)blockIdx.x * 16;
        if (idx > N_NODES - 1) idx = N_NODES - 1;
        s_gmin = batch[idx];
    }
    __syncthreads();

    int t  = blockIdx.x * 256 + tid;
    int n  = t >> 4, sl = t & 15;
    bool valid = n < N_NODES;

    float acc[DIM] = {0.f,0.f,0.f,0.f,0.f,0.f,0.f,0.f,0.f,0.f};
    if (valid) {
        int beg = rowp[n], end = rowp[n + 1];
        for (int j0 = beg + sl * 2; j0 < end; j0 += 32) {
            int   srcs[2];
            uint4 ra[2];
            unsigned rb[2];
#pragma unroll
            for (int k = 0; k < 2; ++k) {
                int jj = j0 + k;
                srcs[k] = __builtin_nontemporal_load(&col[min(jj, end - 1)]);
            }
#pragma unroll
            for (int k = 0; k < 2; ++k) {
                ra[k] = *(const uint4*)&pt[srcs[k] * PH];
                rb[k] = *(const unsigned*)&pt[srcs[k] * PH + 8];
            }
#pragma unroll
            for (int k = 0; k < 2; ++k) {
                float mk = (j0 + k < end) ? 1.f : 0.f;
                float2 f0 = __half22float2(*(__half2*)&ra[k].x);
                float2 f1 = __half22float2(*(__half2*)&ra[k].y);
                float2 f2 = __half22float2(*(__half2*)&ra[k].z);
                float2 f3 = __half22float2(*(__half2*)&ra[k].w);
                float2 f4 = __half22float2(*(__half2*)&rb[k]);
                acc[0] = fmaf(mk, f0.x, acc[0]); acc[1] = fmaf(mk, f0.y, acc[1]);
                acc[2] = fmaf(mk, f1.x, acc[2]); acc[3] = fmaf(mk, f1.y, acc[3]);
                acc[4] = fmaf(mk, f2.x, acc[4]); acc[5] = fmaf(mk, f2.y, acc[5]);
                acc[6] = fmaf(mk, f3.x, acc[6]); acc[7] = fmaf(mk, f3.y, acc[7]);
                acc[8] = fmaf(mk, f4.x, acc[8]); acc[9] = fmaf(mk, f4.y, acc[9]);
            }
        }
    }
#pragma unroll
    for (int f = 0; f < DIM; ++f) {          // DPP reduce across 16 lanes
        acc[f] += __shfl_xor(acc[f], 1);
        acc[f] += __shfl_xor(acc[f], 2);
        acc[f] += __shfl_xor(acc[f], 4);
        acc[f] += __shfl_xor(acc[f], 8);
    }

    if (valid && sl == 0) {
        // own row + bias + relu
        uint4 a = *(const uint4*)&pt[n * PH];
        unsigned b = *(const unsigned*)&pt[n * PH + 8];
        float2 f0 = __half22float2(*(__half2*)&a.x);
        float2 f1 = __half22float2(*(__half2*)&a.y);
        float2 f2 = __half22float2(*(__half2*)&a.z);
        float2 f3 = __half22float2(*(__half2*)&a.w);
        float2 f4 = __half22float2(*(__half2*)&b);
        float u[DIM];
        u[0] = fmaxf(acc[0] + f0.x + s_b1[0], 0.f); u[1] = fmaxf(acc[1] + f0.y + s_b1[1], 0.f);
        u[2] = fmaxf(acc[2] + f1.x + s_b1[2], 0.f); u[3] = fmaxf(acc[3] + f1.y + s_b1[3], 0.f);
        u[4] = fmaxf(acc[4] + f2.x + s_b1[4], 0.f); u[5] = fmaxf(acc[5] + f2.y + s_b1[5], 0.f);
        u[6] = fmaxf(acc[6] + f3.x + s_b1[6], 0.f); u[7] = fmaxf(acc[7] + f3.y + s_b1[7], 0.f);
        u[8] = fmaxf(acc[8] + f4.x + s_b1[8], 0.f); u[9] = fmaxf(acc[9] + f4.y + s_b1[9], 0.f);

        float hv[DIM];
#pragma unroll
        for (int f = 0; f < DIM; ++f) hv[f] = s_b2[f];
#pragma unroll
        for (int j = 0; j < DIM; ++j) {
            float uj = u[j];
            const float4* wr = (const float4*)&s_w2[j * 12];
            float4 wa = wr[0], wb = wr[1];
            float2 wc = *(const float2*)&s_w2[j * 12 + 8];
            hv[0] += uj * wa.x; hv[1] += uj * wa.y; hv[2] += uj * wa.z; hv[3] += uj * wa.w;
            hv[4] += uj * wb.x; hv[5] += uj * wb.y; hv[6] += uj * wb.z; hv[7] += uj * wb.w;
            hv[8] += uj * wc.x; hv[9] += uj * wc.y;
        }
#pragma unroll
        for (int f = 0; f < DIM; ++f) hv[f] = fmaxf(hv[f], 0.f);

        // pool into per-block LDS window (batch sorted; block spans ~1-2 graphs)
        int g = batch[n];
        int slot = g - s_gmin;
        if (slot < PWIN) {
#pragma unroll
            for (int f = 0; f < DIM; ++f) atomicAdd(&s_pool[slot * DIM + f], hv[f]);
        } else {
#pragma unroll
            for (int f = 0; f < DIM; ++f) atomicAdd(&poolL[g * DIM + f], hv[f]);
        }

        if (HAS_NEXT) {
            float pv[DIM];
#pragma unroll
            for (int f = 0; f < DIM; ++f) pv[f] = 0.f;
#pragma unroll
            for (int j = 0; j < DIM; ++j) {
                float hj = hv[j];
                const float4* wr = (const float4*)&s_w1n[j * 12];
                float4 wa = wr[0], wb = wr[1];
                float2 wc = *(const float2*)&s_w1n[j * 12 + 8];
                pv[0] += hj * wa.x; pv[1] += hj * wa.y; pv[2] += hj * wa.z; pv[3] += hj * wa.w;
                pv[4] += hj * wb.x; pv[5] += hj * wb.y; pv[6] += hj * wb.z; pv[7] += hj * wb.w;
                pv[8] += hj * wc.x; pv[9] += hj * wc.y;
            }
            union { __half2 h; unsigned u; } c0, c1, c2, c3, c4;
            c0.h = __floats2half2_rn(pv[0], pv[1]);
            c1.h = __floats2half2_rn(pv[2], pv[3]);
            c2.h = __floats2half2_rn(pv[4], pv[5]);
            c3.h = __floats2half2_rn(pv[6], pv[7]);
            c4.h = __floats2half2_rn(pv[8], pv[9]);
            uint4 s; s.x = c0.u; s.y = c1.u; s.z = c2.u; s.w = c3.u;
            *(uint4*)&pn[n * PH] = s;
            *(unsigned*)&pn[n * PH + 8] = c4.u;
        }
    }
    __syncthreads();
    if (tid < PWIN * DIM) {
        float v = s_pool[tid];
        if (v != 0.f) {
            int g = s_gmin + tid / DIM;
            if (g < N_GRAPHS) atomicAdd(&poolL[g * DIM + (tid % DIM)], v);
        }
    }
}

__global__ void k_out(const float* __restrict__ pool, const int* __restrict__ gptr,
                      const float* __restrict__ l1, const float* __restrict__ l2,
                      const float* __restrict__ l3, const float* __restrict__ l4,
                      const float* __restrict__ l5, float* __restrict__ out) {
    int t = blockIdx.x * blockDim.x + threadIdx.x;
    if (t >= N_GRAPHS * OUT) return;
    int g = t >> 4;
    int o = t & 15;
    float cnt = fmaxf((float)(gptr[g + 1] - gptr[g]), 1.f);
    const float* ls[5] = {l1, l2, l3, l4, l5};
    float acc = 0.f;
#pragma unroll
    for (int l = 0; l < 5; ++l)
#pragma unroll
        for (int f = 0; f < DIM; ++f)
            acc += pool[(l * N_GRAPHS + g) * DIM + f] * ls[l][f * OUT + o];
    out[t] = tanhf(acc / cnt);
}

extern "C" void kernel_launch(void* const* d_in, const int* in_sizes, int n_in,
                              void* d_out, int out_size, void* d_ws, size_t ws_size,
                              hipStream_t stream) {
    const float* x     = (const float*)d_in[0];
    const int*   ei    = (const int*)d_in[1];
    const int*   batch = (const int*)d_in[2];
    const float *w1[5], *b1[5], *w2[5], *b2[5], *lp[5];
    for (int l = 0; l < 5; ++l) {
        w1[l] = (const float*)d_in[3 + l * 4 + 0];
        b1[l] = (const float*)d_in[3 + l * 4 + 1];
        w2[l] = (const float*)d_in[3 + l * 4 + 2];
        b2[l] = (const float*)d_in[3 + l * 4 + 3];
        lp[l] = (const float*)d_in[23 + l];
    }
    float* out = (float*)d_out;

    // workspace (~20 MB)
    ushort* ptA  = (ushort*)d_ws;                       // N*PH ushorts (3.2MB)
    ushort* ptB  = ptA + N_NODES * PH;                  // 3.2MB
    float*  pool = (float*)(ptB + N_NODES * PH);        // 25,600 floats
    int*    gptr = (int*)(pool + 5 * N_GRAPHS * DIM);   // 513 -> pad 516
    int*    bbase= gptr + 516;                          // NBUCK+1 -> pad 392+pad -> 400
    int*    rowp = bbase + 400;                         // 100,001 -> pad 100,004
    int*    col  = rowp + 100004;                       // N_EDGES (+8 slack)
    int*    hist = col + N_EDGES + 8;                   // NBUCK*NBLK_E = 50,048

    hipMemsetAsync(pool, 0, 5 * N_GRAPHS * DIM * sizeof(float), stream);

    k_bounds<<<NBLK, 256, 0, stream>>>(batch, gptr);
    k_proj1<<<NODEBLK, 256, 0, stream>>>(x, w1[0], ptA);

    k_hist<<<NBLK_E, 512, 0, stream>>>(ei, hist);
    k_btot<<<NBUCK, 64, 0, stream>>>(hist, bbase);
    k_bscan<<<1, 1024, 0, stream>>>(bbase, rowp);
    k_colscan<<<NBUCK, NBLK_E, 0, stream>>>(hist, bbase);
    k_bucket<<<NBLK_E, 512, 0, stream>>>(ei, hist, col);
    k_sort<<<NBUCK, 256, 0, stream>>>(bbase, col, rowp);

    ushort* pc  = ptA;
    ushort* pnx = ptB;
    for (int l = 0; l < 5; ++l) {
        float* poolL = pool + l * N_GRAPHS * DIM;
        if (l < 4)
            k_layer<1><<<LAYBLK, 256, 0, stream>>>(pc, rowp, col, batch,
                b1[l], w2[l], b2[l], w1[l + 1], poolL, pnx);
        else
            k_layer<0><<<LAYBLK, 256, 0, stream>>>(pc, rowp, col, batch,
                b1[l], w2[l], b2[l], nullptr, poolL, nullptr);
        ushort* tmp = pc; pc = pnx; pnx = tmp;
    }
    k_out<<<(N_GRAPHS * OUT + 255) / 256, 256, 0, stream>>>(
        pool, gptr, lp[0], lp[1], lp[2], lp[3], lp[4], out);
}

// Round 14
// 260.011 us; speedup vs baseline: 1.1570x; 1.1570x over previous
//
#include <hip/hip_runtime.h>
#include <hip/hip_fp16.h>
#include <math.h>

#define N_NODES  100000
#define N_EDGES  3200000
#define N_GRAPHS 512
#define N_FEAT   128
#define DIM      10
#define PH       16      // fp16 row stride (halves) = 32B, row 32B-aligned
#define OUT      16
#define NBLK     ((N_NODES + 255) / 256)

#define BW       256                         // nodes per bucket (small frontier line set)
#define BSHIFT   8
#define NBUCK    ((N_NODES + BW - 1) / BW)   // 391
#define NBLK_E   256                         // blocks in edge passes (full-chip TLP)
#define EPB      ((N_EDGES + NBLK_E - 1) / NBLK_E)  // 12500
#define CAP      12288                       // LDS edge staging per bucket (48KB)
#define NODEBLK  ((N_NODES + 63) / 64)       // 1563 blocks of 64 nodes
#define LAYBLK   ((N_NODES * 8 + 255) / 256) // 3125 blocks, 32 nodes each
#define PWIN     8                           // LDS pool window (graphs per block)

// gptr[g] = first node with batch >= g (batch sorted). gptr[N_GRAPHS] = N_NODES.
__global__ void k_bounds(const int* __restrict__ batch, int* __restrict__ gptr) {
    int n = blockIdx.x * blockDim.x + threadIdx.x;
    if (n >= N_NODES) return;
    int bn = batch[n];
    int bp = (n == 0) ? -1 : batch[n - 1];
    for (int g = bp + 1; g <= bn; ++g) gptr[g] = n;
    if (n == N_NODES - 1)
        for (int g = bn + 1; g <= N_GRAPHS; ++g) gptr[g] = N_NODES;
}

// p[n] = x[n] @ w1 (128->10). 4 lanes/node, interleaved k, DPP-only reduce.
__global__ void k_proj1(const float* __restrict__ x, const float* __restrict__ w1,
                        ushort* __restrict__ pt) {
    __shared__ __align__(16) float s_w1[N_FEAT * 12];
    int tid = threadIdx.x;
    for (int i = tid; i < N_FEAT * DIM; i += 256) {
        int k = i / DIM, f = i - k * DIM;
        s_w1[k * 12 + f] = w1[i];
    }
    __syncthreads();
    int n  = blockIdx.x * 64 + (tid >> 2);
    int sl = tid & 3;
    if (n >= N_NODES) return;

    float4 xv[8];
#pragma unroll
    for (int i = 0; i < 8; ++i)
        xv[i] = *(const float4*)&x[n * N_FEAT + i * 16 + sl * 4];

    float acc[DIM] = {0.f,0.f,0.f,0.f,0.f,0.f,0.f,0.f,0.f,0.f};
#pragma unroll
    for (int i = 0; i < 8; ++i) {
#pragma unroll
        for (int c = 0; c < 4; ++c) {
            float xk = (c == 0) ? xv[i].x : (c == 1) ? xv[i].y : (c == 2) ? xv[i].z : xv[i].w;
            const float* wr = &s_w1[(i * 16 + sl * 4 + c) * 12];
            float4 wa = *(const float4*)wr;
            float4 wb = *(const float4*)(wr + 4);
            float2 wc = *(const float2*)(wr + 8);
            acc[0] += xk * wa.x; acc[1] += xk * wa.y; acc[2] += xk * wa.z; acc[3] += xk * wa.w;
            acc[4] += xk * wb.x; acc[5] += xk * wb.y; acc[6] += xk * wb.z; acc[7] += xk * wb.w;
            acc[8] += xk * wc.x; acc[9] += xk * wc.y;
        }
    }
#pragma unroll
    for (int f = 0; f < DIM; ++f) {
        acc[f] += __shfl_xor(acc[f], 1);
        acc[f] += __shfl_xor(acc[f], 2);
    }
    if (sl == 0) {
        union { __half2 h; unsigned u; } c0, c1, c2, c3, c4;
        c0.h = __floats2half2_rn(acc[0], acc[1]);
        c1.h = __floats2half2_rn(acc[2], acc[3]);
        c2.h = __floats2half2_rn(acc[4], acc[5]);
        c3.h = __floats2half2_rn(acc[6], acc[7]);
        c4.h = __floats2half2_rn(acc[8], acc[9]);
        uint4 s; s.x = c0.u; s.y = c1.u; s.z = c2.u; s.w = c3.u;
        *(uint4*)&pt[n * PH] = s;
        *(unsigned*)&pt[n * PH + 8] = c4.u;
    }
}

// ---- deterministic bucket sort of edges by dst>>BSHIFT (no global atomics) ----
__global__ void k_hist(const int* __restrict__ ei, int* __restrict__ hist) {
    __shared__ int s_h[NBUCK];
    for (int i = threadIdx.x; i < NBUCK; i += blockDim.x) s_h[i] = 0;
    __syncthreads();
    int base = blockIdx.x * EPB;
    int end  = min(base + EPB, N_EDGES);
    for (int e = base + threadIdx.x; e < end; e += blockDim.x)
        atomicAdd(&s_h[ei[N_EDGES + e] >> BSHIFT], 1);
    __syncthreads();
    for (int i = threadIdx.x; i < NBUCK; i += blockDim.x)
        hist[i * NBLK_E + blockIdx.x] = s_h[i];
}

__global__ void k_btot(const int* __restrict__ hist, int* __restrict__ bbase) {
    int b = blockIdx.x, lane = threadIdx.x;
    int t = 0;
    for (int k = lane; k < NBLK_E; k += 64) t += hist[b * NBLK_E + k];
    t += __shfl_xor(t, 32); t += __shfl_xor(t, 16); t += __shfl_xor(t, 8);
    t += __shfl_xor(t, 4);  t += __shfl_xor(t, 2);  t += __shfl_xor(t, 1);
    if (lane == 0) bbase[b] = t;
}

__global__ void k_bscan(int* __restrict__ bbase, int* __restrict__ rowp) {
    __shared__ int s[1024];
    int tid = threadIdx.x;
    int v = (tid < NBUCK) ? bbase[tid] : 0;
    s[tid] = v;
    __syncthreads();
    for (int off = 1; off < 1024; off <<= 1) {
        int w = (tid >= off) ? s[tid - off] : 0;
        __syncthreads();
        s[tid] += w;
        __syncthreads();
    }
    if (tid < NBUCK) bbase[tid] = s[tid] - v;
    if (tid == 0) { bbase[NBUCK] = s[1023]; rowp[N_NODES] = s[1023]; }
}

__global__ void k_colscan(int* __restrict__ hist, const int* __restrict__ bbase) {
    __shared__ int s[NBLK_E];
    int b = blockIdx.x, tid = threadIdx.x;
    int v = hist[b * NBLK_E + tid];
    s[tid] = v;
    __syncthreads();
    for (int off = 1; off < NBLK_E; off <<= 1) {
        int w = (tid >= off) ? s[tid - off] : 0;
        __syncthreads();
        s[tid] += w;
        __syncthreads();
    }
    hist[b * NBLK_E + tid] = bbase[b] + s[tid] - v;
}

__global__ void k_bucket(const int* __restrict__ ei, const int* __restrict__ off,
                         int* __restrict__ col) {
    __shared__ int loc[NBUCK];
    for (int i = threadIdx.x; i < NBUCK; i += blockDim.x)
        loc[i] = off[i * NBLK_E + blockIdx.x];
    __syncthreads();
    int base = blockIdx.x * EPB;
    int end  = min(base + EPB, N_EDGES);
    for (int e = base + threadIdx.x; e < end; e += blockDim.x) {
        int src = ei[e];
        int dst = ei[N_EDGES + e];
        int bkt = dst >> BSHIFT;
        int pos = atomicAdd(&loc[bkt], 1);         // LDS atomic
        col[pos] = ((dst & (BW - 1)) << 17) | src;
    }
}

__global__ void k_sort(const int* __restrict__ bbase, int* __restrict__ col,
                       int* __restrict__ rowp) {
    __shared__ int s_e[CAP];
    __shared__ int s_cnt[BW];
    __shared__ int s_scan[BW];
    __shared__ int s_cur[BW];
    int b = blockIdx.x, tid = threadIdx.x;
    int beg = bbase[b], end = bbase[b + 1], m = end - beg;
    for (int i = tid; i < m; i += 256) s_e[i] = col[beg + i];
    if (tid < BW) s_cnt[tid] = 0;
    __syncthreads();
    for (int i = tid; i < m; i += 256) atomicAdd(&s_cnt[s_e[i] >> 17], 1);
    __syncthreads();
    if (tid < BW) s_scan[tid] = s_cnt[tid];
    __syncthreads();
    for (int off = 1; off < BW; off <<= 1) {
        int v = (tid < BW && tid >= off) ? s_scan[tid - off] : 0;
        __syncthreads();
        if (tid < BW) s_scan[tid] += v;
        __syncthreads();
    }
    if (tid < BW) {
        int excl = s_scan[tid] - s_cnt[tid];
        s_cur[tid] = excl;
        int n = b * BW + tid;
        if (n < N_NODES) rowp[n] = beg + excl;
    }
    __syncthreads();
    for (int i = tid; i < m; i += 256) {
        int pk = s_e[i];
        int pos = atomicAdd(&s_cur[pk >> 17], 1);
        col[beg + pos] = pk & 0x1FFFF;
    }
}

// ---- fused layer: 8 lanes/node batched gather + lane0 MLP + LDS-window pool + proj ----
template <int HAS_NEXT>
__global__ void k_layer(const ushort* __restrict__ pt, const int* __restrict__ rowp,
                        const int* __restrict__ col, const int* __restrict__ batch,
                        const float* __restrict__ b1, const float* __restrict__ w2,
                        const float* __restrict__ b2, const float* __restrict__ w1n,
                        float* __restrict__ poolL, ushort* __restrict__ pn) {
    __shared__ __align__(16) float s_w2[120], s_w1n[120];
    __shared__ float s_b1[DIM], s_b2[DIM];
    __shared__ float s_pool[PWIN * DIM];
    __shared__ int s_gmin;
    int tid = threadIdx.x;
    if (tid < 120) {
        int j = tid / 12, f = tid - j * 12;
        s_w2[tid] = (f < 10) ? w2[j * 10 + f] : 0.f;
        if (HAS_NEXT) s_w1n[tid] = (f < 10) ? w1n[j * 10 + f] : 0.f;
    }
    if (tid < DIM) { s_b1[tid] = b1[tid]; s_b2[tid] = b2[tid]; }
    if (tid < PWIN * DIM) s_pool[tid] = 0.f;
    if (tid == 0) {
        int idx = (int)blockIdx.x * 32;
        if (idx > N_NODES - 1) idx = N_NODES - 1;
        s_gmin = batch[idx];
    }
    __syncthreads();

    int t  = blockIdx.x * 256 + tid;
    int n  = t >> 3, sl = t & 7;
    bool valid = n < N_NODES;

    float acc[DIM] = {0.f,0.f,0.f,0.f,0.f,0.f,0.f,0.f,0.f,0.f};
    if (valid) {
        int beg = rowp[n], end = rowp[n + 1];
        for (int j0 = beg + sl * 4; j0 < end; j0 += 32) {
            int   srcs[4];
            uint4 ra[4];
            unsigned rb[4];
#pragma unroll
            for (int k = 0; k < 4; ++k) {
                int jj = j0 + k;
                srcs[k] = __builtin_nontemporal_load(&col[min(jj, end - 1)]);
            }
#pragma unroll
            for (int k = 0; k < 4; ++k) {
                ra[k] = *(const uint4*)&pt[srcs[k] * PH];
                rb[k] = *(const unsigned*)&pt[srcs[k] * PH + 8];
            }
#pragma unroll
            for (int k = 0; k < 4; ++k) {
                float mk = (j0 + k < end) ? 1.f : 0.f;
                float2 f0 = __half22float2(*(__half2*)&ra[k].x);
                float2 f1 = __half22float2(*(__half2*)&ra[k].y);
                float2 f2 = __half22float2(*(__half2*)&ra[k].z);
                float2 f3 = __half22float2(*(__half2*)&ra[k].w);
                float2 f4 = __half22float2(*(__half2*)&rb[k]);
                acc[0] = fmaf(mk, f0.x, acc[0]); acc[1] = fmaf(mk, f0.y, acc[1]);
                acc[2] = fmaf(mk, f1.x, acc[2]); acc[3] = fmaf(mk, f1.y, acc[3]);
                acc[4] = fmaf(mk, f2.x, acc[4]); acc[5] = fmaf(mk, f2.y, acc[5]);
                acc[6] = fmaf(mk, f3.x, acc[6]); acc[7] = fmaf(mk, f3.y, acc[7]);
                acc[8] = fmaf(mk, f4.x, acc[8]); acc[9] = fmaf(mk, f4.y, acc[9]);
            }
        }
    }
#pragma unroll
    for (int f = 0; f < DIM; ++f) {          // DPP reduce across 8 lanes
        acc[f] += __shfl_xor(acc[f], 1);
        acc[f] += __shfl_xor(acc[f], 2);
        acc[f] += __shfl_xor(acc[f], 4);
    }

    if (valid && sl == 0) {
        // own row + bias + relu
        uint4 a = *(const uint4*)&pt[n * PH];
        unsigned b = *(const unsigned*)&pt[n * PH + 8];
        float2 f0 = __half22float2(*(__half2*)&a.x);
        float2 f1 = __half22float2(*(__half2*)&a.y);
        float2 f2 = __half22float2(*(__half2*)&a.z);
        float2 f3 = __half22float2(*(__half2*)&a.w);
        float2 f4 = __half22float2(*(__half2*)&b);
        float u[DIM];
        u[0] = fmaxf(acc[0] + f0.x + s_b1[0], 0.f); u[1] = fmaxf(acc[1] + f0.y + s_b1[1], 0.f);
        u[2] = fmaxf(acc[2] + f1.x + s_b1[2], 0.f); u[3] = fmaxf(acc[3] + f1.y + s_b1[3], 0.f);
        u[4] = fmaxf(acc[4] + f2.x + s_b1[4], 0.f); u[5] = fmaxf(acc[5] + f2.y + s_b1[5], 0.f);
        u[6] = fmaxf(acc[6] + f3.x + s_b1[6], 0.f); u[7] = fmaxf(acc[7] + f3.y + s_b1[7], 0.f);
        u[8] = fmaxf(acc[8] + f4.x + s_b1[8], 0.f); u[9] = fmaxf(acc[9] + f4.y + s_b1[9], 0.f);

        float hv[DIM];
#pragma unroll
        for (int f = 0; f < DIM; ++f) hv[f] = s_b2[f];
#pragma unroll
        for (int j = 0; j < DIM; ++j) {
            float uj = u[j];
            const float4* wr = (const float4*)&s_w2[j * 12];
            float4 wa = wr[0], wb = wr[1];
            float2 wc = *(const float2*)&s_w2[j * 12 + 8];
            hv[0] += uj * wa.x; hv[1] += uj * wa.y; hv[2] += uj * wa.z; hv[3] += uj * wa.w;
            hv[4] += uj * wb.x; hv[5] += uj * wb.y; hv[6] += uj * wb.z; hv[7] += uj * wb.w;
            hv[8] += uj * wc.x; hv[9] += uj * wc.y;
        }
#pragma unroll
        for (int f = 0; f < DIM; ++f) hv[f] = fmaxf(hv[f], 0.f);

        // pool into per-block LDS window (batch sorted; block spans ~1-2 graphs)
        int g = batch[n];
        int slot = g - s_gmin;
        if (slot < PWIN) {
#pragma unroll
            for (int f = 0; f < DIM; ++f) atomicAdd(&s_pool[slot * DIM + f], hv[f]);
        } else {
#pragma unroll
            for (int f = 0; f < DIM; ++f) atomicAdd(&poolL[g * DIM + f], hv[f]);
        }

        if (HAS_NEXT) {
            float pv[DIM];
#pragma unroll
            for (int f = 0; f < DIM; ++f) pv[f] = 0.f;
#pragma unroll
            for (int j = 0; j < DIM; ++j) {
                float hj = hv[j];
                const float4* wr = (const float4*)&s_w1n[j * 12];
                float4 wa = wr[0], wb = wr[1];
                float2 wc = *(const float2*)&s_w1n[j * 12 + 8];
                pv[0] += hj * wa.x; pv[1] += hj * wa.y; pv[2] += hj * wa.z; pv[3] += hj * wa.w;
                pv[4] += hj * wb.x; pv[5] += hj * wb.y; pv[6] += hj * wb.z; pv[7] += hj * wb.w;
                pv[8] += hj * wc.x; pv[9] += hj * wc.y;
            }
            union { __half2 h; unsigned u; } c0, c1, c2, c3, c4;
            c0.h = __floats2half2_rn(pv[0], pv[1]);
            c1.h = __floats2half2_rn(pv[2], pv[3]);
            c2.h = __floats2half2_rn(pv[4], pv[5]);
            c3.h = __floats2half2_rn(pv[6], pv[7]);
            c4.h = __floats2half2_rn(pv[8], pv[9]);
            uint4 s; s.x = c0.u; s.y = c1.u; s.z = c2.u; s.w = c3.u;
            *(uint4*)&pn[n * PH] = s;
            *(unsigned*)&pn[n * PH + 8] = c4.u;
        }
    }
    __syncthreads();
    if (tid < PWIN * DIM) {
        float v = s_pool[tid];
        if (v != 0.f) {
            int g = s_gmin + tid / DIM;
            if (g < N_GRAPHS) atomicAdd(&poolL[g * DIM + (tid % DIM)], v);
        }
    }
}

__global__ void k_out(const float* __restrict__ pool, const int* __restrict__ gptr,
                      const float* __restrict__ l1, const float* __restrict__ l2,
                      const float* __restrict__ l3, const float* __restrict__ l4,
                      const float* __restrict__ l5, float* __restrict__ out) {
    int t = blockIdx.x * blockDim.x + threadIdx.x;
    if (t >= N_GRAPHS * OUT) return;
    int g = t >> 4;
    int o = t & 15;
    float cnt = fmaxf((float)(gptr[g + 1] - gptr[g]), 1.f);
    const float* ls[5] = {l1, l2, l3, l4, l5};
    float acc = 0.f;
#pragma unroll
    for (int l = 0; l < 5; ++l)
#pragma unroll
        for (int f = 0; f < DIM; ++f)
            acc += pool[(l * N_GRAPHS + g) * DIM + f] * ls[l][f * OUT + o];
    out[t] = tanhf(acc / cnt);
}

extern "C" void kernel_launch(void* const* d_in, const int* in_sizes, int n_in,
                              void* d_out, int out_size, void* d_ws, size_t ws_size,
                              hipStream_t stream) {
    const float* x     = (const float*)d_in[0];
    const int*   ei    = (const int*)d_in[1];
    const int*   batch = (const int*)d_in[2];
    const float *w1[5], *b1[5], *w2[5], *b2[5], *lp[5];
    for (int l = 0; l < 5; ++l) {
        w1[l] = (const float*)d_in[3 + l * 4 + 0];
        b1[l] = (const float*)d_in[3 + l * 4 + 1];
        w2[l] = (const float*)d_in[3 + l * 4 + 2];
        b2[l] = (const float*)d_in[3 + l * 4 + 3];
        lp[l] = (const float*)d_in[23 + l];
    }
    float* out = (float*)d_out;

    // workspace (~20 MB)
    ushort* ptA  = (ushort*)d_ws;                       // N*PH ushorts (3.2MB)
    ushort* ptB  = ptA + N_NODES * PH;                  // 3.2MB
    float*  pool = (float*)(ptB + N_NODES * PH);        // 25,600 floats
    int*    gptr = (int*)(pool + 5 * N_GRAPHS * DIM);   // 513 -> pad 516
    int*    bbase= gptr + 516;                          // NBUCK+1 -> pad 400
    int*    rowp = bbase + 400;                         // 100,001 -> pad 100,004
    int*    col  = rowp + 100004;                       // N_EDGES (+8 slack)
    int*    hist = col + N_EDGES + 8;                   // NBUCK*NBLK_E = 100,096

    hipMemsetAsync(pool, 0, 5 * N_GRAPHS * DIM * sizeof(float), stream);

    k_bounds<<<NBLK, 256, 0, stream>>>(batch, gptr);
    k_proj1<<<NODEBLK, 256, 0, stream>>>(x, w1[0], ptA);

    k_hist<<<NBLK_E, 512, 0, stream>>>(ei, hist);
    k_btot<<<NBUCK, 64, 0, stream>>>(hist, bbase);
    k_bscan<<<1, 1024, 0, stream>>>(bbase, rowp);
    k_colscan<<<NBUCK, NBLK_E, 0, stream>>>(hist, bbase);
    k_bucket<<<NBLK_E, 512, 0, stream>>>(ei, hist, col);
    k_sort<<<NBUCK, 256, 0, stream>>>(bbase, col, rowp);

    ushort* pc  = ptA;
    ushort* pnx = ptB;
    for (int l = 0; l < 5; ++l) {
        float* poolL = pool + l * N_GRAPHS * DIM;
        if (l < 4)
            k_layer<1><<<LAYBLK, 256, 0, stream>>>(pc, rowp, col, batch,
                b1[l], w2[l], b2[l], w1[l + 1], poolL, pnx);
        else
            k_layer<0><<<LAYBLK, 256, 0, stream>>>(pc, rowp, col, batch,
                b1[l], w2[l], b2[l], nullptr, poolL, nullptr);
        ushort* tmp = pc; pc = pnx; pnx = tmp;
    }
    k_out<<<(N_GRAPHS * OUT + 255) / 256, 256, 0, stream>>>(
        pool, gptr, lp[0], lp[1], lp[2], lp[3], lp[4], out);
}

// Round 15
// 258.015 us; speedup vs baseline: 1.1659x; 1.0077x over previous
//
#include <hip/hip_runtime.h>
#include <hip/hip_fp16.h>
#include <math.h>

#define N_NODES  100000
#define N_EDGES  3200000
#define N_GRAPHS 512
#define N_FEAT   128
#define DIM      10
#define PH       16      // fp16 row stride (halves) = 32B, row 32B-aligned
#define OUT      16
#define NBLK     ((N_NODES + 255) / 256)

#define BW       256                         // nodes per bucket (small frontier line set)
#define BSHIFT   8
#define NBUCK    ((N_NODES + BW - 1) / BW)   // 391
#define NBLK_E   256                         // blocks in edge passes (full-chip TLP)
#define EPB      ((N_EDGES + NBLK_E - 1) / NBLK_E)  // 12500
#define CAP      12288                       // LDS edge staging per bucket (48KB)
#define NODEBLK  ((N_NODES + 63) / 64)       // 1563 blocks of 64 nodes
#define LAYBLK   ((N_NODES * 8 + 255) / 256) // 3125 blocks, 32 nodes each
#define PWIN     8                           // LDS pool window (graphs per block)

// gptr[g] = first node with batch >= g (batch sorted). gptr[N_GRAPHS] = N_NODES.
// Also zeroes the 5*G*DIM pool accumulator (avoids the runtime's 40us fill kernel).
__global__ void k_bounds(const int* __restrict__ batch, int* __restrict__ gptr,
                         float* __restrict__ pool) {
    int n = blockIdx.x * blockDim.x + threadIdx.x;
    if (n < 5 * N_GRAPHS * DIM) pool[n] = 0.f;
    if (n >= N_NODES) return;
    int bn = batch[n];
    int bp = (n == 0) ? -1 : batch[n - 1];
    for (int g = bp + 1; g <= bn; ++g) gptr[g] = n;
    if (n == N_NODES - 1)
        for (int g = bn + 1; g <= N_GRAPHS; ++g) gptr[g] = N_NODES;
}

// p[n] = x[n] @ w1 (128->10). 4 lanes/node, interleaved k, DPP-only reduce.
__global__ void k_proj1(const float* __restrict__ x, const float* __restrict__ w1,
                        ushort* __restrict__ pt) {
    __shared__ __align__(16) float s_w1[N_FEAT * 12];
    int tid = threadIdx.x;
    for (int i = tid; i < N_FEAT * DIM; i += 256) {
        int k = i / DIM, f = i - k * DIM;
        s_w1[k * 12 + f] = w1[i];
    }
    __syncthreads();
    int n  = blockIdx.x * 64 + (tid >> 2);
    int sl = tid & 3;
    if (n >= N_NODES) return;

    float4 xv[8];
#pragma unroll
    for (int i = 0; i < 8; ++i)
        xv[i] = *(const float4*)&x[n * N_FEAT + i * 16 + sl * 4];

    float acc[DIM] = {0.f,0.f,0.f,0.f,0.f,0.f,0.f,0.f,0.f,0.f};
#pragma unroll
    for (int i = 0; i < 8; ++i) {
#pragma unroll
        for (int c = 0; c < 4; ++c) {
            float xk = (c == 0) ? xv[i].x : (c == 1) ? xv[i].y : (c == 2) ? xv[i].z : xv[i].w;
            const float* wr = &s_w1[(i * 16 + sl * 4 + c) * 12];
            float4 wa = *(const float4*)wr;
            float4 wb = *(const float4*)(wr + 4);
            float2 wc = *(const float2*)(wr + 8);
            acc[0] += xk * wa.x; acc[1] += xk * wa.y; acc[2] += xk * wa.z; acc[3] += xk * wa.w;
            acc[4] += xk * wb.x; acc[5] += xk * wb.y; acc[6] += xk * wb.z; acc[7] += xk * wb.w;
            acc[8] += xk * wc.x; acc[9] += xk * wc.y;
        }
    }
#pragma unroll
    for (int f = 0; f < DIM; ++f) {
        acc[f] += __shfl_xor(acc[f], 1);
        acc[f] += __shfl_xor(acc[f], 2);
    }
    if (sl == 0) {
        union { __half2 h; unsigned u; } c0, c1, c2, c3, c4;
        c0.h = __floats2half2_rn(acc[0], acc[1]);
        c1.h = __floats2half2_rn(acc[2], acc[3]);
        c2.h = __floats2half2_rn(acc[4], acc[5]);
        c3.h = __floats2half2_rn(acc[6], acc[7]);
        c4.h = __floats2half2_rn(acc[8], acc[9]);
        uint4 s; s.x = c0.u; s.y = c1.u; s.z = c2.u; s.w = c3.u;
        *(uint4*)&pt[n * PH] = s;
        *(unsigned*)&pt[n * PH + 8] = c4.u;
    }
}

// ---- deterministic bucket sort of edges by dst>>BSHIFT (no global atomics) ----
__global__ void k_hist(const int* __restrict__ ei, int* __restrict__ hist) {
    __shared__ int s_h[NBUCK];
    for (int i = threadIdx.x; i < NBUCK; i += blockDim.x) s_h[i] = 0;
    __syncthreads();
    int base = blockIdx.x * EPB;
    int end  = min(base + EPB, N_EDGES);
    for (int e = base + threadIdx.x; e < end; e += blockDim.x)
        atomicAdd(&s_h[ei[N_EDGES + e] >> BSHIFT], 1);
    __syncthreads();
    for (int i = threadIdx.x; i < NBUCK; i += blockDim.x)
        hist[i * NBLK_E + blockIdx.x] = s_h[i];
}

__global__ void k_btot(const int* __restrict__ hist, int* __restrict__ bbase) {
    int b = blockIdx.x, lane = threadIdx.x;
    int t = 0;
    for (int k = lane; k < NBLK_E; k += 64) t += hist[b * NBLK_E + k];
    t += __shfl_xor(t, 32); t += __shfl_xor(t, 16); t += __shfl_xor(t, 8);
    t += __shfl_xor(t, 4);  t += __shfl_xor(t, 2);  t += __shfl_xor(t, 1);
    if (lane == 0) bbase[b] = t;
}

__global__ void k_bscan(int* __restrict__ bbase, int* __restrict__ rowp) {
    __shared__ int s[1024];
    int tid = threadIdx.x;
    int v = (tid < NBUCK) ? bbase[tid] : 0;
    s[tid] = v;
    __syncthreads();
    for (int off = 1; off < 1024; off <<= 1) {
        int w = (tid >= off) ? s[tid - off] : 0;
        __syncthreads();
        s[tid] += w;
        __syncthreads();
    }
    if (tid < NBUCK) bbase[tid] = s[tid] - v;
    if (tid == 0) { bbase[NBUCK] = s[1023]; rowp[N_NODES] = s[1023]; }
}

__global__ void k_colscan(int* __restrict__ hist, const int* __restrict__ bbase) {
    __shared__ int s[NBLK_E];
    int b = blockIdx.x, tid = threadIdx.x;
    int v = hist[b * NBLK_E + tid];
    s[tid] = v;
    __syncthreads();
    for (int off = 1; off < NBLK_E; off <<= 1) {
        int w = (tid >= off) ? s[tid - off] : 0;
        __syncthreads();
        s[tid] += w;
        __syncthreads();
    }
    hist[b * NBLK_E + tid] = bbase[b] + s[tid] - v;
}

__global__ void k_bucket(const int* __restrict__ ei, const int* __restrict__ off,
                         int* __restrict__ col) {
    __shared__ int loc[NBUCK];
    for (int i = threadIdx.x; i < NBUCK; i += blockDim.x)
        loc[i] = off[i * NBLK_E + blockIdx.x];
    __syncthreads();
    int base = blockIdx.x * EPB;
    int end  = min(base + EPB, N_EDGES);
    for (int e = base + threadIdx.x; e < end; e += blockDim.x) {
        int src = ei[e];
        int dst = ei[N_EDGES + e];
        int bkt = dst >> BSHIFT;
        int pos = atomicAdd(&loc[bkt], 1);         // LDS atomic
        col[pos] = ((dst & (BW - 1)) << 17) | src;
    }
}

__global__ void k_sort(const int* __restrict__ bbase, int* __restrict__ col,
                       int* __restrict__ rowp) {
    __shared__ int s_e[CAP];
    __shared__ int s_cnt[BW];
    __shared__ int s_scan[BW];
    __shared__ int s_cur[BW];
    int b = blockIdx.x, tid = threadIdx.x;
    int beg = bbase[b], end = bbase[b + 1], m = end - beg;
    for (int i = tid; i < m; i += 256) s_e[i] = col[beg + i];
    if (tid < BW) s_cnt[tid] = 0;
    __syncthreads();
    for (int i = tid; i < m; i += 256) atomicAdd(&s_cnt[s_e[i] >> 17], 1);
    __syncthreads();
    if (tid < BW) s_scan[tid] = s_cnt[tid];
    __syncthreads();
    for (int off = 1; off < BW; off <<= 1) {
        int v = (tid < BW && tid >= off) ? s_scan[tid - off] : 0;
        __syncthreads();
        if (tid < BW) s_scan[tid] += v;
        __syncthreads();
    }
    if (tid < BW) {
        int excl = s_scan[tid] - s_cnt[tid];
        s_cur[tid] = excl;
        int n = b * BW + tid;
        if (n < N_NODES) rowp[n] = beg + excl;
    }
    __syncthreads();
    for (int i = tid; i < m; i += 256) {
        int pk = s_e[i];
        int pos = atomicAdd(&s_cur[pk >> 17], 1);
        col[beg + pos] = pk & 0x1FFFF;
    }
}

// ---- fused layer: 8 lanes/node batched gather + lane0 MLP + LDS-window pool + proj ----
template <int HAS_NEXT>
__global__ void k_layer(const ushort* __restrict__ pt, const int* __restrict__ rowp,
                        const int* __restrict__ col, const int* __restrict__ batch,
                        const float* __restrict__ b1, const float* __restrict__ w2,
                        const float* __restrict__ b2, const float* __restrict__ w1n,
                        float* __restrict__ poolL, ushort* __restrict__ pn) {
    __shared__ __align__(16) float s_w2[120], s_w1n[120];
    __shared__ float s_b1[DIM], s_b2[DIM];
    __shared__ float s_pool[PWIN * DIM];
    __shared__ int s_gmin;
    int tid = threadIdx.x;
    if (tid < 120) {
        int j = tid / 12, f = tid - j * 12;
        s_w2[tid] = (f < 10) ? w2[j * 10 + f] : 0.f;
        if (HAS_NEXT) s_w1n[tid] = (f < 10) ? w1n[j * 10 + f] : 0.f;
    }
    if (tid < DIM) { s_b1[tid] = b1[tid]; s_b2[tid] = b2[tid]; }
    if (tid < PWIN * DIM) s_pool[tid] = 0.f;
    if (tid == 0) {
        int idx = (int)blockIdx.x * 32;
        if (idx > N_NODES - 1) idx = N_NODES - 1;
        s_gmin = batch[idx];
    }
    __syncthreads();

    int t  = blockIdx.x * 256 + tid;
    int n  = t >> 3, sl = t & 7;
    bool valid = n < N_NODES;

    float acc[DIM] = {0.f,0.f,0.f,0.f,0.f,0.f,0.f,0.f,0.f,0.f};
    if (valid) {
        int beg = rowp[n], end = rowp[n + 1];
        for (int j0 = beg + sl * 4; j0 < end; j0 += 32) {
            int   srcs[4];
            uint4 ra[4];
            unsigned rb[4];
#pragma unroll
            for (int k = 0; k < 4; ++k) {
                int jj = j0 + k;
                srcs[k] = __builtin_nontemporal_load(&col[min(jj, end - 1)]);
            }
#pragma unroll
            for (int k = 0; k < 4; ++k) {
                ra[k] = *(const uint4*)&pt[srcs[k] * PH];
                rb[k] = *(const unsigned*)&pt[srcs[k] * PH + 8];
            }
#pragma unroll
            for (int k = 0; k < 4; ++k) {
                float mk = (j0 + k < end) ? 1.f : 0.f;
                float2 f0 = __half22float2(*(__half2*)&ra[k].x);
                float2 f1 = __half22float2(*(__half2*)&ra[k].y);
                float2 f2 = __half22float2(*(__half2*)&ra[k].z);
                float2 f3 = __half22float2(*(__half2*)&ra[k].w);
                float2 f4 = __half22float2(*(__half2*)&rb[k]);
                acc[0] = fmaf(mk, f0.x, acc[0]); acc[1] = fmaf(mk, f0.y, acc[1]);
                acc[2] = fmaf(mk, f1.x, acc[2]); acc[3] = fmaf(mk, f1.y, acc[3]);
                acc[4] = fmaf(mk, f2.x, acc[4]); acc[5] = fmaf(mk, f2.y, acc[5]);
                acc[6] = fmaf(mk, f3.x, acc[6]); acc[7] = fmaf(mk, f3.y, acc[7]);
                acc[8] = fmaf(mk, f4.x, acc[8]); acc[9] = fmaf(mk, f4.y, acc[9]);
            }
        }
    }
#pragma unroll
    for (int f = 0; f < DIM; ++f) {          // DPP reduce across 8 lanes
        acc[f] += __shfl_xor(acc[f], 1);
        acc[f] += __shfl_xor(acc[f], 2);
        acc[f] += __shfl_xor(acc[f], 4);
    }

    if (valid && sl == 0) {
        // own row + bias + relu
        uint4 a = *(const uint4*)&pt[n * PH];
        unsigned b = *(const unsigned*)&pt[n * PH + 8];
        float2 f0 = __half22float2(*(__half2*)&a.x);
        float2 f1 = __half22float2(*(__half2*)&a.y);
        float2 f2 = __half22float2(*(__half2*)&a.z);
        float2 f3 = __half22float2(*(__half2*)&a.w);
        float2 f4 = __half22float2(*(__half2*)&b);
        float u[DIM];
        u[0] = fmaxf(acc[0] + f0.x + s_b1[0], 0.f); u[1] = fmaxf(acc[1] + f0.y + s_b1[1], 0.f);
        u[2] = fmaxf(acc[2] + f1.x + s_b1[2], 0.f); u[3] = fmaxf(acc[3] + f1.y + s_b1[3], 0.f);
        u[4] = fmaxf(acc[4] + f2.x + s_b1[4], 0.f); u[5] = fmaxf(acc[5] + f2.y + s_b1[5], 0.f);
        u[6] = fmaxf(acc[6] + f3.x + s_b1[6], 0.f); u[7] = fmaxf(acc[7] + f3.y + s_b1[7], 0.f);
        u[8] = fmaxf(acc[8] + f4.x + s_b1[8], 0.f); u[9] = fmaxf(acc[9] + f4.y + s_b1[9], 0.f);

        float hv[DIM];
#pragma unroll
        for (int f = 0; f < DIM; ++f) hv[f] = s_b2[f];
#pragma unroll
        for (int j = 0; j < DIM; ++j) {
            float uj = u[j];
            const float4* wr = (const float4*)&s_w2[j * 12];
            float4 wa = wr[0], wb = wr[1];
            float2 wc = *(const float2*)&s_w2[j * 12 + 8];
            hv[0] += uj * wa.x; hv[1] += uj * wa.y; hv[2] += uj * wa.z; hv[3] += uj * wa.w;
            hv[4] += uj * wb.x; hv[5] += uj * wb.y; hv[6] += uj * wb.z; hv[7] += uj * wb.w;
            hv[8] += uj * wc.x; hv[9] += uj * wc.y;
        }
#pragma unroll
        for (int f = 0; f < DIM; ++f) hv[f] = fmaxf(hv[f], 0.f);

        // pool into per-block LDS window (batch sorted; block spans ~1-2 graphs)
        int g = batch[n];
        int slot = g - s_gmin;
        if (slot < PWIN) {
#pragma unroll
            for (int f = 0; f < DIM; ++f) atomicAdd(&s_pool[slot * DIM + f], hv[f]);
        } else {
#pragma unroll
            for (int f = 0; f < DIM; ++f) atomicAdd(&poolL[g * DIM + f], hv[f]);
        }

        if (HAS_NEXT) {
            float pv[DIM];
#pragma unroll
            for (int f = 0; f < DIM; ++f) pv[f] = 0.f;
#pragma unroll
            for (int j = 0; j < DIM; ++j) {
                float hj = hv[j];
                const float4* wr = (const float4*)&s_w1n[j * 12];
                float4 wa = wr[0], wb = wr[1];
                float2 wc = *(const float2*)&s_w1n[j * 12 + 8];
                pv[0] += hj * wa.x; pv[1] += hj * wa.y; pv[2] += hj * wa.z; pv[3] += hj * wa.w;
                pv[4] += hj * wb.x; pv[5] += hj * wb.y; pv[6] += hj * wb.z; pv[7] += hj * wb.w;
                pv[8] += hj * wc.x; pv[9] += hj * wc.y;
            }
            union { __half2 h; unsigned u; } c0, c1, c2, c3, c4;
            c0.h = __floats2half2_rn(pv[0], pv[1]);
            c1.h = __floats2half2_rn(pv[2], pv[3]);
            c2.h = __floats2half2_rn(pv[4], pv[5]);
            c3.h = __floats2half2_rn(pv[6], pv[7]);
            c4.h = __floats2half2_rn(pv[8], pv[9]);
            uint4 s; s.x = c0.u; s.y = c1.u; s.z = c2.u; s.w = c3.u;
            *(uint4*)&pn[n * PH] = s;
            *(unsigned*)&pn[n * PH + 8] = c4.u;
        }
    }
    __syncthreads();
    if (tid < PWIN * DIM) {
        float v = s_pool[tid];
        if (v != 0.f) {
            int g = s_gmin + tid / DIM;
            if (g < N_GRAPHS) atomicAdd(&poolL[g * DIM + (tid % DIM)], v);
        }
    }
}

__global__ void k_out(const float* __restrict__ pool, const int* __restrict__ gptr,
                      const float* __restrict__ l1, const float* __restrict__ l2,
                      const float* __restrict__ l3, const float* __restrict__ l4,
                      const float* __restrict__ l5, float* __restrict__ out) {
    int t = blockIdx.x * blockDim.x + threadIdx.x;
    if (t >= N_GRAPHS * OUT) return;
    int g = t >> 4;
    int o = t & 15;
    float cnt = fmaxf((float)(gptr[g + 1] - gptr[g]), 1.f);
    const float* ls[5] = {l1, l2, l3, l4, l5};
    float acc = 0.f;
#pragma unroll
    for (int l = 0; l < 5; ++l)
#pragma unroll
        for (int f = 0; f < DIM; ++f)
            acc += pool[(l * N_GRAPHS + g) * DIM + f] * ls[l][f * OUT + o];
    out[t] = tanhf(acc / cnt);
}

extern "C" void kernel_launch(void* const* d_in, const int* in_sizes, int n_in,
                              void* d_out, int out_size, void* d_ws, size_t ws_size,
                              hipStream_t stream) {
    const float* x     = (const float*)d_in[0];
    const int*   ei    = (const int*)d_in[1];
    const int*   batch = (const int*)d_in[2];
    const float *w1[5], *b1[5], *w2[5], *b2[5], *lp[5];
    for (int l = 0; l < 5; ++l) {
        w1[l] = (const float*)d_in[3 + l * 4 + 0];
        b1[l] = (const float*)d_in[3 + l * 4 + 1];
        w2[l] = (const float*)d_in[3 + l * 4 + 2];
        b2[l] = (const float*)d_in[3 + l * 4 + 3];
        lp[l] = (const float*)d_in[23 + l];
    }
    float* out = (float*)d_out;

    // workspace (~20 MB)
    ushort* ptA  = (ushort*)d_ws;                       // N*PH ushorts (3.2MB)
    ushort* ptB  = ptA + N_NODES * PH;                  // 3.2MB
    float*  pool = (float*)(ptB + N_NODES * PH);        // 25,600 floats
    int*    gptr = (int*)(pool + 5 * N_GRAPHS * DIM);   // 513 -> pad 516
    int*    bbase= gptr + 516;                          // NBUCK+1 -> pad 400
    int*    rowp = bbase + 400;                         // 100,001 -> pad 100,004
    int*    col  = rowp + 100004;                       // N_EDGES (+8 slack)
    int*    hist = col + N_EDGES + 8;                   // NBUCK*NBLK_E = 100,096

    k_bounds<<<NBLK, 256, 0, stream>>>(batch, gptr, pool);
    k_proj1<<<NODEBLK, 256, 0, stream>>>(x, w1[0], ptA);

    k_hist<<<NBLK_E, 512, 0, stream>>>(ei, hist);
    k_btot<<<NBUCK, 64, 0, stream>>>(hist, bbase);
    k_bscan<<<1, 1024, 0, stream>>>(bbase, rowp);
    k_colscan<<<NBUCK, NBLK_E, 0, stream>>>(hist, bbase);
    k_bucket<<<NBLK_E, 512, 0, stream>>>(ei, hist, col);
    k_sort<<<NBUCK, 256, 0, stream>>>(bbase, col, rowp);

    ushort* pc  = ptA;
    ushort* pnx = ptB;
    for (int l = 0; l < 5; ++l) {
        float* poolL = pool + l * N_GRAPHS * DIM;
        if (l < 4)
            k_layer<1><<<LAYBLK, 256, 0, stream>>>(pc, rowp, col, batch,
                b1[l], w2[l], b2[l], w1[l + 1], poolL, pnx);
        else
            k_layer<0><<<LAYBLK, 256, 0, stream>>>(pc, rowp, col, batch,
                b1[l], w2[l], b2[l], nullptr, poolL, nullptr);
        ushort* tmp = pc; pc = pnx; pnx = tmp;
    }
    k_out<<<(N_GRAPHS * OUT + 255) / 256, 256, 0, stream>>>(
        pool, gptr, lp[0], lp[1], lp[2], lp[3], lp[4], out);
}

// Round 16
// 257.989 us; speedup vs baseline: 1.1661x; 1.0001x over previous
//
#include <hip/hip_runtime.h>
#include <hip/hip_fp16.h>
#include <math.h>

#define N_NODES  100000
#define N_EDGES  3200000
#define N_GRAPHS 512
#define N_FEAT   128
#define DIM      10
#define PH       16      // fp16 row stride (halves) = 32B, row 32B-aligned
#define OUT      16
#define NBLK     ((N_NODES + 255) / 256)

#define BW       256                         // nodes per bucket (small frontier line set)
#define BSHIFT   8
#define NBUCK    ((N_NODES + BW - 1) / BW)   // 391
#define NBLK_E   256                         // blocks in edge passes (full-chip TLP)
#define EPB      ((N_EDGES + NBLK_E - 1) / NBLK_E)  // 12500
#define CAP      12288                       // LDS edge staging per bucket (48KB)
#define NODEBLK  ((N_NODES + 63) / 64)       // 1563 blocks of 64 nodes
#define LAYBLK   ((N_NODES * 8 + 255) / 256) // 3125 blocks, 32 nodes each
#define PWIN     8                           // LDS pool window (graphs per block)

// gptr[g] = first node with batch >= g (batch sorted). gptr[N_GRAPHS] = N_NODES.
// Also zeroes the 5*G*DIM pool accumulator.
__global__ void k_bounds(const int* __restrict__ batch, int* __restrict__ gptr,
                         float* __restrict__ pool) {
    int n = blockIdx.x * blockDim.x + threadIdx.x;
    if (n < 5 * N_GRAPHS * DIM) pool[n] = 0.f;
    if (n >= N_NODES) return;
    int bn = batch[n];
    int bp = (n == 0) ? -1 : batch[n - 1];
    for (int g = bp + 1; g <= bn; ++g) gptr[g] = n;
    if (n == N_NODES - 1)
        for (int g = bn + 1; g <= N_GRAPHS; ++g) gptr[g] = N_NODES;
}

// p[n] = x[n] @ w1 (128->10). 4 lanes/node, interleaved k, DPP-only reduce.
__global__ void k_proj1(const float* __restrict__ x, const float* __restrict__ w1,
                        ushort* __restrict__ pt) {
    __shared__ __align__(16) float s_w1[N_FEAT * 12];
    int tid = threadIdx.x;
    for (int i = tid; i < N_FEAT * DIM; i += 256) {
        int k = i / DIM, f = i - k * DIM;
        s_w1[k * 12 + f] = w1[i];
    }
    __syncthreads();
    int n  = blockIdx.x * 64 + (tid >> 2);
    int sl = tid & 3;
    if (n >= N_NODES) return;

    float4 xv[8];
#pragma unroll
    for (int i = 0; i < 8; ++i)
        xv[i] = *(const float4*)&x[n * N_FEAT + i * 16 + sl * 4];

    float acc[DIM] = {0.f,0.f,0.f,0.f,0.f,0.f,0.f,0.f,0.f,0.f};
#pragma unroll
    for (int i = 0; i < 8; ++i) {
#pragma unroll
        for (int c = 0; c < 4; ++c) {
            float xk = (c == 0) ? xv[i].x : (c == 1) ? xv[i].y : (c == 2) ? xv[i].z : xv[i].w;
            const float* wr = &s_w1[(i * 16 + sl * 4 + c) * 12];
            float4 wa = *(const float4*)wr;
            float4 wb = *(const float4*)(wr + 4);
            float2 wc = *(const float2*)(wr + 8);
            acc[0] += xk * wa.x; acc[1] += xk * wa.y; acc[2] += xk * wa.z; acc[3] += xk * wa.w;
            acc[4] += xk * wb.x; acc[5] += xk * wb.y; acc[6] += xk * wb.z; acc[7] += xk * wb.w;
            acc[8] += xk * wc.x; acc[9] += xk * wc.y;
        }
    }
#pragma unroll
    for (int f = 0; f < DIM; ++f) {
        acc[f] += __shfl_xor(acc[f], 1);
        acc[f] += __shfl_xor(acc[f], 2);
    }
    if (sl == 0) {
        union { __half2 h; unsigned u; } c0, c1, c2, c3, c4;
        c0.h = __floats2half2_rn(acc[0], acc[1]);
        c1.h = __floats2half2_rn(acc[2], acc[3]);
        c2.h = __floats2half2_rn(acc[4], acc[5]);
        c3.h = __floats2half2_rn(acc[6], acc[7]);
        c4.h = __floats2half2_rn(acc[8], acc[9]);
        uint4 s; s.x = c0.u; s.y = c1.u; s.z = c2.u; s.w = c3.u;
        *(uint4*)&pt[n * PH] = s;
        *(unsigned*)&pt[n * PH + 8] = c4.u;
    }
}

// ---- deterministic bucket sort of edges by dst>>BSHIFT (no global atomics) ----
__global__ void k_hist(const int* __restrict__ ei, int* __restrict__ hist) {
    __shared__ int s_h[NBUCK];
    for (int i = threadIdx.x; i < NBUCK; i += blockDim.x) s_h[i] = 0;
    __syncthreads();
    int base = blockIdx.x * EPB;
    int end  = min(base + EPB, N_EDGES);
    for (int e = base + threadIdx.x; e < end; e += blockDim.x)
        atomicAdd(&s_h[ei[N_EDGES + e] >> BSHIFT], 1);
    __syncthreads();
    for (int i = threadIdx.x; i < NBUCK; i += blockDim.x)
        hist[i * NBLK_E + blockIdx.x] = s_h[i];
}

__global__ void k_btot(const int* __restrict__ hist, int* __restrict__ bbase) {
    int b = blockIdx.x, lane = threadIdx.x;
    int t = 0;
    for (int k = lane; k < NBLK_E; k += 64) t += hist[b * NBLK_E + k];
    t += __shfl_xor(t, 32); t += __shfl_xor(t, 16); t += __shfl_xor(t, 8);
    t += __shfl_xor(t, 4);  t += __shfl_xor(t, 2);  t += __shfl_xor(t, 1);
    if (lane == 0) bbase[b] = t;
}

__global__ void k_bscan(int* __restrict__ bbase, int* __restrict__ rowp) {
    __shared__ int s[1024];
    int tid = threadIdx.x;
    int v = (tid < NBUCK) ? bbase[tid] : 0;
    s[tid] = v;
    __syncthreads();
    for (int off = 1; off < 1024; off <<= 1) {
        int w = (tid >= off) ? s[tid - off] : 0;
        __syncthreads();
        s[tid] += w;
        __syncthreads();
    }
    if (tid < NBUCK) bbase[tid] = s[tid] - v;
    if (tid == 0) { bbase[NBUCK] = s[1023]; rowp[N_NODES] = s[1023]; }
}

__global__ void k_colscan(int* __restrict__ hist, const int* __restrict__ bbase) {
    __shared__ int s[NBLK_E];
    int b = blockIdx.x, tid = threadIdx.x;
    int v = hist[b * NBLK_E + tid];
    s[tid] = v;
    __syncthreads();
    for (int off = 1; off < NBLK_E; off <<= 1) {
        int w = (tid >= off) ? s[tid - off] : 0;
        __syncthreads();
        s[tid] += w;
        __syncthreads();
    }
    hist[b * NBLK_E + tid] = bbase[b] + s[tid] - v;
}

__global__ void k_bucket(const int* __restrict__ ei, const int* __restrict__ off,
                         int* __restrict__ col) {
    __shared__ int loc[NBUCK];
    for (int i = threadIdx.x; i < NBUCK; i += blockDim.x)
        loc[i] = off[i * NBLK_E + blockIdx.x];
    __syncthreads();
    int base = blockIdx.x * EPB;
    int end  = min(base + EPB, N_EDGES);
    for (int e = base + threadIdx.x; e < end; e += blockDim.x) {
        int src = ei[e];
        int dst = ei[N_EDGES + e];
        int bkt = dst >> BSHIFT;
        int pos = atomicAdd(&loc[bkt], 1);         // LDS atomic
        col[pos] = ((dst & (BW - 1)) << 17) | src;
    }
}

__global__ void k_sort(const int* __restrict__ bbase, int* __restrict__ col,
                       int* __restrict__ rowp) {
    __shared__ int s_e[CAP];
    __shared__ int s_cnt[BW];
    __shared__ int s_scan[BW];
    __shared__ int s_cur[BW];
    int b = blockIdx.x, tid = threadIdx.x;
    int beg = bbase[b], end = bbase[b + 1], m = end - beg;
    for (int i = tid; i < m; i += 256) s_e[i] = col[beg + i];
    if (tid < BW) s_cnt[tid] = 0;
    __syncthreads();
    for (int i = tid; i < m; i += 256) atomicAdd(&s_cnt[s_e[i] >> 17], 1);
    __syncthreads();
    if (tid < BW) s_scan[tid] = s_cnt[tid];
    __syncthreads();
    for (int off = 1; off < BW; off <<= 1) {
        int v = (tid < BW && tid >= off) ? s_scan[tid - off] : 0;
        __syncthreads();
        if (tid < BW) s_scan[tid] += v;
        __syncthreads();
    }
    if (tid < BW) {
        int excl = s_scan[tid] - s_cnt[tid];
        s_cur[tid] = excl;
        int n = b * BW + tid;
        if (n < N_NODES) rowp[n] = beg + excl;
    }
    __syncthreads();
    for (int i = tid; i < m; i += 256) {
        int pk = s_e[i];
        int pos = atomicAdd(&s_cur[pk >> 17], 1);
        col[beg + pos] = pk & 0x1FFFF;
    }
}

// ---- fused layer: 8 lanes/node, vectorized col load, hoisted own-row, LDS pool ----
template <int HAS_NEXT>
__global__ void k_layer(const ushort* __restrict__ pt, const int* __restrict__ rowp,
                        const int* __restrict__ col, const int* __restrict__ batch,
                        const float* __restrict__ b1, const float* __restrict__ w2,
                        const float* __restrict__ b2, const float* __restrict__ w1n,
                        float* __restrict__ poolL, ushort* __restrict__ pn) {
    __shared__ __align__(16) float s_w2[120], s_w1n[120];
    __shared__ float s_b1[DIM], s_b2[DIM];
    __shared__ float s_pool[PWIN * DIM];
    __shared__ int s_gmin;
    int tid = threadIdx.x;
    if (tid < 120) {
        int j = tid / 12, f = tid - j * 12;
        s_w2[tid] = (f < 10) ? w2[j * 10 + f] : 0.f;
        if (HAS_NEXT) s_w1n[tid] = (f < 10) ? w1n[j * 10 + f] : 0.f;
    }
    if (tid < DIM) { s_b1[tid] = b1[tid]; s_b2[tid] = b2[tid]; }
    if (tid < PWIN * DIM) s_pool[tid] = 0.f;
    if (tid == 0) {
        int idx = (int)blockIdx.x * 32;
        if (idx > N_NODES - 1) idx = N_NODES - 1;
        s_gmin = batch[idx];
    }
    __syncthreads();

    int t  = blockIdx.x * 256 + tid;
    int n  = t >> 3, sl = t & 7;
    bool valid = n < N_NODES;

    // hoist own-row load (used by sl==0 epilogue) so its latency hides under the gather
    uint4 own_a = make_uint4(0u, 0u, 0u, 0u);
    unsigned own_b = 0u;
    if (valid && sl == 0) {
        own_a = *(const uint4*)&pt[n * PH];
        own_b = *(const unsigned*)&pt[n * PH + 8];
    }

    float acc[DIM] = {0.f,0.f,0.f,0.f,0.f,0.f,0.f,0.f,0.f,0.f};
    if (valid) {
        int beg = rowp[n], end = rowp[n + 1];
        for (int j0 = beg + sl * 4; j0 < end; j0 += 32) {
            int srcs[4];
            if (j0 + 3 < end) {               // one dwordx4 instead of 4 dword loads
                int4 sv;
                __builtin_memcpy(&sv, &col[j0], 16);
                srcs[0] = sv.x; srcs[1] = sv.y; srcs[2] = sv.z; srcs[3] = sv.w;
            } else {
#pragma unroll
                for (int k = 0; k < 4; ++k)
                    srcs[k] = col[min(j0 + k, end - 1)];
            }
            uint4 ra[4];
            unsigned rb[4];
#pragma unroll
            for (int k = 0; k < 4; ++k) {
                ra[k] = *(const uint4*)&pt[srcs[k] * PH];
                rb[k] = *(const unsigned*)&pt[srcs[k] * PH + 8];
            }
#pragma unroll
            for (int k = 0; k < 4; ++k) {
                float mk = (j0 + k < end) ? 1.f : 0.f;
                float2 f0 = __half22float2(*(__half2*)&ra[k].x);
                float2 f1 = __half22float2(*(__half2*)&ra[k].y);
                float2 f2 = __half22float2(*(__half2*)&ra[k].z);
                float2 f3 = __half22float2(*(__half2*)&ra[k].w);
                float2 f4 = __half22float2(*(__half2*)&rb[k]);
                acc[0] = fmaf(mk, f0.x, acc[0]); acc[1] = fmaf(mk, f0.y, acc[1]);
                acc[2] = fmaf(mk, f1.x, acc[2]); acc[3] = fmaf(mk, f1.y, acc[3]);
                acc[4] = fmaf(mk, f2.x, acc[4]); acc[5] = fmaf(mk, f2.y, acc[5]);
                acc[6] = fmaf(mk, f3.x, acc[6]); acc[7] = fmaf(mk, f3.y, acc[7]);
                acc[8] = fmaf(mk, f4.x, acc[8]); acc[9] = fmaf(mk, f4.y, acc[9]);
            }
        }
    }
#pragma unroll
    for (int f = 0; f < DIM; ++f) {          // DPP reduce across 8 lanes
        acc[f] += __shfl_xor(acc[f], 1);
        acc[f] += __shfl_xor(acc[f], 2);
        acc[f] += __shfl_xor(acc[f], 4);
    }

    if (valid && sl == 0) {
        float2 f0 = __half22float2(*(__half2*)&own_a.x);
        float2 f1 = __half22float2(*(__half2*)&own_a.y);
        float2 f2 = __half22float2(*(__half2*)&own_a.z);
        float2 f3 = __half22float2(*(__half2*)&own_a.w);
        float2 f4 = __half22float2(*(__half2*)&own_b);
        float u[DIM];
        u[0] = fmaxf(acc[0] + f0.x + s_b1[0], 0.f); u[1] = fmaxf(acc[1] + f0.y + s_b1[1], 0.f);
        u[2] = fmaxf(acc[2] + f1.x + s_b1[2], 0.f); u[3] = fmaxf(acc[3] + f1.y + s_b1[3], 0.f);
        u[4] = fmaxf(acc[4] + f2.x + s_b1[4], 0.f); u[5] = fmaxf(acc[5] + f2.y + s_b1[5], 0.f);
        u[6] = fmaxf(acc[6] + f3.x + s_b1[6], 0.f); u[7] = fmaxf(acc[7] + f3.y + s_b1[7], 0.f);
        u[8] = fmaxf(acc[8] + f4.x + s_b1[8], 0.f); u[9] = fmaxf(acc[9] + f4.y + s_b1[9], 0.f);

        float hv[DIM];
#pragma unroll
        for (int f = 0; f < DIM; ++f) hv[f] = s_b2[f];
#pragma unroll
        for (int j = 0; j < DIM; ++j) {
            float uj = u[j];
            const float4* wr = (const float4*)&s_w2[j * 12];
            float4 wa = wr[0], wb = wr[1];
            float2 wc = *(const float2*)&s_w2[j * 12 + 8];
            hv[0] += uj * wa.x; hv[1] += uj * wa.y; hv[2] += uj * wa.z; hv[3] += uj * wa.w;
            hv[4] += uj * wb.x; hv[5] += uj * wb.y; hv[6] += uj * wb.z; hv[7] += uj * wb.w;
            hv[8] += uj * wc.x; hv[9] += uj * wc.y;
        }
#pragma unroll
        for (int f = 0; f < DIM; ++f) hv[f] = fmaxf(hv[f], 0.f);

        // pool into per-block LDS window (batch sorted; block spans ~1-2 graphs)
        int g = batch[n];
        int slot = g - s_gmin;
        if (slot < PWIN) {
#pragma unroll
            for (int f = 0; f < DIM; ++f) atomicAdd(&s_pool[slot * DIM + f], hv[f]);
        } else {
#pragma unroll
            for (int f = 0; f < DIM; ++f) atomicAdd(&poolL[g * DIM + f], hv[f]);
        }

        if (HAS_NEXT) {
            float pv[DIM];
#pragma unroll
            for (int f = 0; f < DIM; ++f) pv[f] = 0.f;
#pragma unroll
            for (int j = 0; j < DIM; ++j) {
                float hj = hv[j];
                const float4* wr = (const float4*)&s_w1n[j * 12];
                float4 wa = wr[0], wb = wr[1];
                float2 wc = *(const float2*)&s_w1n[j * 12 + 8];
                pv[0] += hj * wa.x; pv[1] += hj * wa.y; pv[2] += hj * wa.z; pv[3] += hj * wa.w;
                pv[4] += hj * wb.x; pv[5] += hj * wb.y; pv[6] += hj * wb.z; pv[7] += hj * wb.w;
                pv[8] += hj * wc.x; pv[9] += hj * wc.y;
            }
            union { __half2 h; unsigned u; } c0, c1, c2, c3, c4;
            c0.h = __floats2half2_rn(pv[0], pv[1]);
            c1.h = __floats2half2_rn(pv[2], pv[3]);
            c2.h = __floats2half2_rn(pv[4], pv[5]);
            c3.h = __floats2half2_rn(pv[6], pv[7]);
            c4.h = __floats2half2_rn(pv[8], pv[9]);
            uint4 s; s.x = c0.u; s.y = c1.u; s.z = c2.u; s.w = c3.u;
            *(uint4*)&pn[n * PH] = s;
            *(unsigned*)&pn[n * PH + 8] = c4.u;
        }
    }
    __syncthreads();
    if (tid < PWIN * DIM) {
        float v = s_pool[tid];
        if (v != 0.f) {
            int g = s_gmin + tid / DIM;
            if (g < N_GRAPHS) atomicAdd(&poolL[g * DIM + (tid % DIM)], v);
        }
    }
}

__global__ void k_out(const float* __restrict__ pool, const int* __restrict__ gptr,
                      const float* __restrict__ l1, const float* __restrict__ l2,
                      const float* __restrict__ l3, const float* __restrict__ l4,
                      const float* __restrict__ l5, float* __restrict__ out) {
    int t = blockIdx.x * blockDim.x + threadIdx.x;
    if (t >= N_GRAPHS * OUT) return;
    int g = t >> 4;
    int o = t & 15;
    float cnt = fmaxf((float)(gptr[g + 1] - gptr[g]), 1.f);
    const float* ls[5] = {l1, l2, l3, l4, l5};
    float acc = 0.f;
#pragma unroll
    for (int l = 0; l < 5; ++l)
#pragma unroll
        for (int f = 0; f < DIM; ++f)
            acc += pool[(l * N_GRAPHS + g) * DIM + f] * ls[l][f * OUT + o];
    out[t] = tanhf(acc / cnt);
}

extern "C" void kernel_launch(void* const* d_in, const int* in_sizes, int n_in,
                              void* d_out, int out_size, void* d_ws, size_t ws_size,
                              hipStream_t stream) {
    const float* x     = (const float*)d_in[0];
    const int*   ei    = (const int*)d_in[1];
    const int*   batch = (const int*)d_in[2];
    const float *w1[5], *b1[5], *w2[5], *b2[5], *lp[5];
    for (int l = 0; l < 5; ++l) {
        w1[l] = (const float*)d_in[3 + l * 4 + 0];
        b1[l] = (const float*)d_in[3 + l * 4 + 1];
        w2[l] = (const float*)d_in[3 + l * 4 + 2];
        b2[l] = (const float*)d_in[3 + l * 4 + 3];
        lp[l] = (const float*)d_in[23 + l];
    }
    float* out = (float*)d_out;

    // workspace (~20 MB)
    ushort* ptA  = (ushort*)d_ws;                       // N*PH ushorts (3.2MB)
    ushort* ptB  = ptA + N_NODES * PH;                  // 3.2MB
    float*  pool = (float*)(ptB + N_NODES * PH);        // 25,600 floats
    int*    gptr = (int*)(pool + 5 * N_GRAPHS * DIM);   // 513 -> pad 516
    int*    bbase= gptr + 516;                          // NBUCK+1 -> pad 400
    int*    rowp = bbase + 400;                         // 100,001 -> pad 100,004
    int*    col  = rowp + 100004;                       // N_EDGES (+8 slack)
    int*    hist = col + N_EDGES + 8;                   // NBUCK*NBLK_E = 100,096

    k_bounds<<<NBLK, 256, 0, stream>>>(batch, gptr, pool);
    k_proj1<<<NODEBLK, 256, 0, stream>>>(x, w1[0], ptA);

    k_hist<<<NBLK_E, 512, 0, stream>>>(ei, hist);
    k_btot<<<NBUCK, 64, 0, stream>>>(hist, bbase);
    k_bscan<<<1, 1024, 0, stream>>>(bbase, rowp);
    k_colscan<<<NBUCK, NBLK_E, 0, stream>>>(hist, bbase);
    k_bucket<<<NBLK_E, 512, 0, stream>>>(ei, hist, col);
    k_sort<<<NBUCK, 256, 0, stream>>>(bbase, col, rowp);

    ushort* pc  = ptA;
    ushort* pnx = ptB;
    for (int l = 0; l < 5; ++l) {
        float* poolL = pool + l * N_GRAPHS * DIM;
        if (l < 4)
            k_layer<1><<<LAYBLK, 256, 0, stream>>>(pc, rowp, col, batch,
                b1[l], w2[l], b2[l], w1[l + 1], poolL, pnx);
        else
            k_layer<0><<<LAYBLK, 256, 0, stream>>>(pc, rowp, col, batch,
                b1[l], w2[l], b2[l], nullptr, poolL, nullptr);
        ushort* tmp = pc; pc = pnx; pnx = tmp;
    }
    k_out<<<(N_GRAPHS * OUT + 255) / 256, 256, 0, stream>>>(
        pool, gptr, lp[0], lp[1], lp[2], lp[3], lp[4], out);
}